// Round 1
// baseline (5140.418 us; speedup 1.0000x reference)
//
#include <hip/hip_runtime.h>
#include <hip/hip_bf16.h>

#define NL 4
#define NB 4
#define NS 512
#define NH 1024
#define NV 32000
#define RING 8

typedef unsigned int u32;
typedef unsigned short u16;
typedef __attribute__((ext_vector_type(8))) __bf16 vbf16x8;
typedef __attribute__((ext_vector_type(8))) u16   vu16x8;
typedef __attribute__((ext_vector_type(4))) u32   vu32x4;
typedef __attribute__((ext_vector_type(4))) float vf32x4;

__device__ __forceinline__ u16 f2bf(float f) {
    u32 x = __builtin_bit_cast(u32, f);
    x += 0x7FFFu + ((x >> 16) & 1u);
    return (u16)(x >> 16);
}
__device__ __forceinline__ float softplus_f(float x) {
    return fmaxf(x, 0.0f) + log1pf(expf(-fabsf(x)));
}
__device__ __forceinline__ void spin_ge(int* p, int tgt) {
    // relaxed agent-scope polling; safety cap so a bug degrades to wrong-answer, not a hang
    for (int i = 0; i < (1 << 22); ++i) {
        if (__hip_atomic_load(p, __ATOMIC_RELAXED, __HIP_MEMORY_SCOPE_AGENT) >= tgt) return;
        __builtin_amdgcn_s_sleep(1);
    }
}

// ---------------- persistent recurrence kernel ----------------
// 256 WGs (1/CU). layer = bid&3 (XCD-local-ish), slice = bid>>2 (64 slices x 16 rows).
// Weights (bf16) live in VGPRs as MFMA B-fragments for the entire kernel.
// wave w handles matrix w: 0=Ws(x hp), 1=Us(x in), 2=tau_wh(x hp), 3=tau_wu(x in).

#define APAD 8
#define ASTR (NH + APAD)

__global__ __launch_bounds__(256, 1) void lnn_recur(
    const int* __restrict__ ids, const float* __restrict__ emb,
    const float* __restrict__ Ws, const float* __restrict__ Us,
    const float* __restrict__ bsv, const float* __restrict__ twh,
    const float* __restrict__ twu, const float* __restrict__ tbv,
    const float* __restrict__ lambda_p,
    int* prod_flag, int* cons_flag,
    u16* ring, u16* out_bf16, float* hT_out)
{
    __shared__ __align__(16) u16 act_hp[5][ASTR];   // rows 0..3 = batch, row 4 = zeros (A-row clamp)
    __shared__ __align__(16) u16 act_in[5][ASTR];
    __shared__ float cross[4][16][4];               // [mat][j][b]
    __shared__ float bias_a[16], bias_t[16];

    const int bid   = blockIdx.x;
    const int layer = bid & 3;
    const int slice = bid >> 2;
    const int j0    = slice << 4;
    const int tid   = threadIdx.x;
    const int wave  = tid >> 6;
    const int lane  = tid & 63;

    // ---- load this wave's weight matrix rows as MFMA B-fragments (bf16, registers) ----
    const float* msel0 = (wave == 0) ? Ws : (wave == 1) ? Us : (wave == 2) ? twh : twu;
    const float* mat = msel0 + (size_t)layer * NH * NH;
    const int jr = j0 + (lane & 15);        // B "col" = output row j
    const int kb = (lane >> 4) * 8;         // k offset within 32-chunk
    vbf16x8 wfrag[32];
#pragma unroll
    for (int c = 0; c < 32; ++c) {
        const float* s = mat + (size_t)jr * NH + c * 32 + kb;
        vu16x8 t8;
#pragma unroll
        for (int e = 0; e < 8; ++e) t8[e] = f2bf(s[e]);
        wfrag[c] = __builtin_bit_cast(vbf16x8, t8);
    }

    for (int i = tid; i < ASTR; i += 256) { act_hp[4][i] = 0; act_in[4][i] = 0; }
    if (tid < 16) {
        bias_a[tid] = bsv[layer * NH + j0 + tid];
        bias_t[tid] = tbv[layer * NH + j0 + tid];
    }
    const float lam = softplus_f(lambda_p[0]);
    float hreg = 0.0f;                       // wave0: (j = lane&15, b = lane>>4)

    const int lm1 = (layer > 0) ? layer - 1 : 0;
    int* pf      = prod_flag + layer * NS;
    int* pf_prev = prod_flag + lm1 * NS;
    int* cfp     = cons_flag + layer * NS;
    int* cfm     = cons_flag + lm1 * NS;

    for (int t = 0; t < NS; ++t) {
        // ---- 1. wait for inputs (thread 0 polls; acquire = cross-XCD inv) ----
        if (tid == 0) {
            bool acq = false;
            if (t > 0)     { spin_ge(pf + t - 1, 64); acq = true; }
            if (layer > 0) { spin_ge(pf_prev + t, 64); acq = true; }
            if (layer < 3 && t >= RING) spin_ge(cfp + t - RING, 64);
            if (acq) {
                int* ap = (t > 0) ? (pf + t - 1) : (pf_prev + t);
                (void)__hip_atomic_load(ap, __ATOMIC_ACQUIRE, __HIP_MEMORY_SCOPE_AGENT);
            }
        }
        __syncthreads();

        // ---- 2. stage activations to LDS (bf16) ----
        {
            const int b  = tid >> 6;
            const int k0 = (tid & 63) << 4;      // 16 elems / thread
            u16* dh = &act_hp[b][k0];
            if (t == 0) {
                vu16x8 z = {0,0,0,0,0,0,0,0};
                *(vu16x8*)dh = z; *(vu16x8*)(dh + 8) = z;
            } else {
                const u16* s = ring + (((size_t)layer * RING + ((t - 1) & (RING - 1))) * NB + b) * NH + k0;
                *(vu16x8*)dh = *(const vu16x8*)s;
                *(vu16x8*)(dh + 8) = *(const vu16x8*)(s + 8);
            }
            u16* di = &act_in[b][k0];
            if (layer == 0) {
                const int v = ids[b * NS + t];
                const float* er = emb + (size_t)v * NH + k0;
                const vf32x4* ev = (const vf32x4*)er;
                float fb[16];
                *(vf32x4*)&fb[0] = ev[0]; *(vf32x4*)&fb[4]  = ev[1];
                *(vf32x4*)&fb[8] = ev[2]; *(vf32x4*)&fb[12] = ev[3];
                vu16x8 d0, d1;
#pragma unroll
                for (int e = 0; e < 8; ++e) { d0[e] = f2bf(fb[e]); d1[e] = f2bf(fb[8 + e]); }
                *(vu16x8*)di = d0; *(vu16x8*)(di + 8) = d1;
            } else {
                const u16* s = ring + (((size_t)lm1 * RING + (t & (RING - 1))) * NB + b) * NH + k0;
                *(vu16x8*)di = *(const vu16x8*)s;
                *(vu16x8*)(di + 8) = *(const vu16x8*)(s + 8);
            }
        }
        __syncthreads();
        if (tid == 0 && layer > 0)
            __hip_atomic_fetch_add(cfm + t, 1, __ATOMIC_RELAXED, __HIP_MEMORY_SCOPE_AGENT);

        // ---- 3. MFMA: out[j,b] = sum_k act[b,k] * M[j,k] ----
        {
            const u16 (*asrc)[ASTR] = ((wave & 1) == 0) ? act_hp : act_in;
            int ar = lane & 15; if (ar > 4) ar = 4;   // rows 4..15 read the zero row
            vf32x4 acc = {0.f, 0.f, 0.f, 0.f};
#pragma unroll
            for (int c = 0; c < 32; ++c) {
                vbf16x8 af = *(const vbf16x8*)&asrc[ar][c * 32 + kb];
                acc = __builtin_amdgcn_mfma_f32_16x16x32_bf16(af, wfrag[c], acc, 0, 0, 0);
            }
            // D: col = lane&15 (= j), row = (lane>>4)*4 + reg (= b); valid rows live in lanes 0..15
            if (lane < 16) {
#pragma unroll
                for (int r = 0; r < 4; ++r) cross[wave][lane][r] = acc[r];
            }
        }
        __syncthreads();

        // ---- 4. pointwise finalize (wave 0) + publish ----
        if (wave == 0) {
            const int j = lane & 15, b = lane >> 4;
            const float sa = cross[0][j][b] + cross[1][j][b] + bias_a[j];
            const float st = cross[2][j][b] + cross[3][j][b] + bias_t[j];
            const float tau = softplus_f(st) + 0.01f;
            const float a   = tanhf(sa);
            float dx = lam * (a - hreg / tau);
            dx = fminf(10.0f, fmaxf(-10.0f, dx));
            hreg = fmaf(0.1f, dx, hreg);
            const u16 hb = f2bf(hreg);
            ring[(((size_t)layer * RING + (t & (RING - 1))) * NB + b) * NH + j0 + j] = hb;
            if (layer == 3) out_bf16[((size_t)b * NS + t) * NH + j0 + j] = hb;
            if (t == NS - 1) hT_out[((size_t)layer * NB + b) * NH + j0 + j] = hreg;
        }
        if (tid == 0)
            __hip_atomic_fetch_add(pf + t, 1, __ATOMIC_RELEASE, __HIP_MEMORY_SCOPE_AGENT);
    }
}

// ---------------- projection GEMM: C[2048][32000] = A[2048][1024](bf16) * W[32000][1024]^T + b ----
#define BM 128
#define BN 128
#define BK 32
#define KSTEPS (NH / BK)
#define LSTR (BK + 8)   // +8 u16 pad -> conflict-balanced ds_read_b128

__global__ __launch_bounds__(256, 1) void proj_gemm(
    const u16* __restrict__ A, const float* __restrict__ Bw,
    const float* __restrict__ bias, float* __restrict__ C)
{
    __shared__ __align__(16) u16 Asm[2][BM][LSTR];
    __shared__ __align__(16) u16 Bsm[2][BN][LSTR];

    const int tid  = threadIdx.x;
    const int wave = tid >> 6, lane = tid & 63;
    const int wr = wave >> 1, wc = wave & 1;
    const int m0 = blockIdx.y * BM;
    const int n0 = blockIdx.x * BN;

    const int srow  = tid >> 1;
    const int shalf = tid & 1;
    const u16*   agp = A  + (size_t)(m0 + srow) * NH + shalf * 16;
    const float* bgp = Bw + (size_t)(n0 + srow) * NH + shalf * 16;

    vf32x4 zed = {0.f, 0.f, 0.f, 0.f};
    vf32x4 acc[4][4];
#pragma unroll
    for (int m = 0; m < 4; ++m)
#pragma unroll
        for (int n = 0; n < 4; ++n) acc[m][n] = zed;

    vu32x4 areg0, areg1; vf32x4 breg0, breg1, breg2, breg3;
    auto load_tile = [&](int kt) {
        const u16* ap = agp + kt * BK;
        areg0 = *(const vu32x4*)ap;
        areg1 = *(const vu32x4*)(ap + 8);
        const float* bp = bgp + kt * BK;
        breg0 = *(const vf32x4*)bp;       breg1 = *(const vf32x4*)(bp + 4);
        breg2 = *(const vf32x4*)(bp + 8); breg3 = *(const vf32x4*)(bp + 12);
    };
    auto write_tile = [&](int buf) {
        u16* ad = &Asm[buf][srow][shalf * 16];
        *(vu32x4*)ad = areg0; *(vu32x4*)(ad + 8) = areg1;
        float fb[16];
        *(vf32x4*)&fb[0] = breg0; *(vf32x4*)&fb[4]  = breg1;
        *(vf32x4*)&fb[8] = breg2; *(vf32x4*)&fb[12] = breg3;
        vu16x8 v0, v1;
#pragma unroll
        for (int e = 0; e < 8; ++e) { v0[e] = f2bf(fb[e]); v1[e] = f2bf(fb[8 + e]); }
        u16* bd = &Bsm[buf][srow][shalf * 16];
        *(vu16x8*)bd = v0; *(vu16x8*)(bd + 8) = v1;
    };

    load_tile(0); write_tile(0);
    __syncthreads();

    const int fr = lane & 15;
    const int fk = (lane >> 4) * 8;
    for (int kt = 0; kt < KSTEPS; ++kt) {
        const int cur = kt & 1;
        if (kt + 1 < KSTEPS) load_tile(kt + 1);   // issue-early (T14)
        vbf16x8 afr[4], bfr[4];
#pragma unroll
        for (int m = 0; m < 4; ++m)
            afr[m] = *(const vbf16x8*)&Asm[cur][wr * 64 + m * 16 + fr][fk];
#pragma unroll
        for (int n = 0; n < 4; ++n)
            bfr[n] = *(const vbf16x8*)&Bsm[cur][wc * 64 + n * 16 + fr][fk];
#pragma unroll
        for (int m = 0; m < 4; ++m)
#pragma unroll
            for (int n = 0; n < 4; ++n)
                acc[m][n] = __builtin_amdgcn_mfma_f32_16x16x32_bf16(afr[m], bfr[n], acc[m][n], 0, 0, 0);
        if (kt + 1 < KSTEPS) write_tile(cur ^ 1); // write-late
        __syncthreads();
    }

    const int cc = lane & 15;
    const int cr = (lane >> 4) * 4;
#pragma unroll
    for (int m = 0; m < 4; ++m) {
#pragma unroll
        for (int n = 0; n < 4; ++n) {
            const int gc = n0 + wc * 64 + n * 16 + cc;
            const float bval = bias[gc];
            float* cp = C + (size_t)(m0 + wr * 64 + m * 16 + cr) * NV + gc;
#pragma unroll
            for (int r = 0; r < 4; ++r)
                cp[(size_t)r * NV] = acc[m][n][r] + bval;
        }
    }
}

extern "C" void kernel_launch(void* const* d_in, const int* in_sizes, int n_in,
                              void* d_out, int out_size, void* d_ws, size_t ws_size,
                              hipStream_t stream) {
    const int*   ids = (const int*)  d_in[0];
    const float* emb = (const float*)d_in[1];
    const float* pw  = (const float*)d_in[2];
    const float* pb  = (const float*)d_in[3];
    const float* lam = (const float*)d_in[4];
    const float* Ws  = (const float*)d_in[5];
    const float* Us  = (const float*)d_in[6];
    const float* bsv = (const float*)d_in[7];
    const float* twh = (const float*)d_in[8];
    const float* twu = (const float*)d_in[9];
    const float* tbv = (const float*)d_in[10];

    char* ws = (char*)d_ws;
    int* prod_flag = (int*)ws;                           // 4*512*4 = 8 KB
    int* cons_flag = (int*)(ws + 8192);                  // 8 KB
    u16* ring      = (u16*)(ws + 16384);                 // 4*8*4*1024*2 = 256 KB
    u16* out_bf16  = (u16*)(ws + 16384 + 262144);        // 2048*1024*2 = 4 MB

    float* logits = (float*)d_out;
    float* hT     = logits + (size_t)NB * NS * NV;

    hipMemsetAsync(prod_flag, 0, 16384, stream);         // flags must be zero every call
    lnn_recur<<<dim3(256), dim3(256), 0, stream>>>(ids, emb, Ws, Us, bsv, twh, twu, tbv, lam,
                                                   prod_flag, cons_flag, ring, out_bf16, hT);
    proj_gemm<<<dim3(NV / BN, (NB * NS) / BM), dim3(256), 0, stream>>>(out_bf16, pw, pb, logits);
}

// Round 2
// 3633.364 us; speedup vs baseline: 1.4148x; 1.4148x over previous
//
#include <hip/hip_runtime.h>
#include <hip/hip_bf16.h>

#define NL 4
#define NB 4
#define NS 512
#define NH 1024
#define NV 32000
#define RING 8
#define FSTR 16   // flag padding: one 64B line per (layer,t)

typedef unsigned int u32;
typedef unsigned short u16;
typedef __attribute__((ext_vector_type(8))) __bf16 vbf16x8;
typedef __attribute__((ext_vector_type(8))) u16   vu16x8;
typedef __attribute__((ext_vector_type(4))) u32   vu32x4;
typedef __attribute__((ext_vector_type(4))) float vf32x4;
typedef __attribute__((ext_vector_type(2))) float vf32x2;

__device__ __forceinline__ u16 f2bf(float f) {
    u32 x = __builtin_bit_cast(u32, f);
    x += 0x7FFFu + ((x >> 16) & 1u);
    return (u16)(x >> 16);
}
__device__ __forceinline__ float softplus_f(float x) {
    return fmaxf(x, 0.0f) + log1pf(expf(-fabsf(x)));
}
#define ALOAD(p)     __hip_atomic_load((p), __ATOMIC_RELAXED, __HIP_MEMORY_SCOPE_AGENT)
#define ASTORE(p, v) __hip_atomic_store((p), (v), __ATOMIC_RELAXED, __HIP_MEMORY_SCOPE_AGENT)
#define AADD(p, v)   __hip_atomic_fetch_add((p), (v), __ATOMIC_RELAXED, __HIP_MEMORY_SCOPE_AGENT)

// ---------------- persistent recurrence kernel ----------------
// 256 WGs (1/CU). layer = bid&3, slice = bid>>2 (64 slices x 16 rows).
// Weights live in VGPRs as MFMA B-fragments for the whole kernel.
// All cross-block data/flags use relaxed agent-scope atomics (sc1, L2-bypass,
// coherent at IF$) -> no buffer_wbl2 / buffer_inv per step.

#define APAD 8
#define ASTR (NH + APAD)

__global__ __launch_bounds__(256, 1) void lnn_recur(
    const int* __restrict__ ids, const float* __restrict__ emb,
    const float* __restrict__ Ws, const float* __restrict__ Us,
    const float* __restrict__ bsv, const float* __restrict__ twh,
    const float* __restrict__ twu, const float* __restrict__ tbv,
    const float* __restrict__ lambda_p,
    int* prod_flag, int* cons_flag,
    u32* ring_dw, u32* out_dw, float* hT_out)
{
    __shared__ __align__(16) u16 act_hp[5][ASTR];   // rows 0..3 = batch, row 4 = zeros
    __shared__ __align__(16) u16 act_in[5][ASTR];
    __shared__ float cross[4][16][4];               // [mat][j][b]
    __shared__ float bias_a[16], bias_t[16];

    const int bid   = blockIdx.x;
    const int layer = bid & 3;
    const int slice = bid >> 2;
    const int j0    = slice << 4;
    const int tid   = threadIdx.x;
    const int wave  = tid >> 6;
    const int lane  = tid & 63;

    // ---- weight fragments: wave w owns matrix w (0=Ws,1=Us,2=twh,3=twu) ----
    const float* msel0 = (wave == 0) ? Ws : (wave == 1) ? Us : (wave == 2) ? twh : twu;
    const float* mat = msel0 + (size_t)layer * NH * NH;
    const int jr = j0 + (lane & 15);        // B col = output row j
    const int kb = (lane >> 4) * 8;         // k offset within 32-chunk
    vbf16x8 wfrag[32];
#pragma unroll
    for (int c = 0; c < 32; ++c) {
        const float* s = mat + (size_t)jr * NH + c * 32 + kb;
        vu16x8 t8;
#pragma unroll
        for (int e = 0; e < 8; ++e) t8[e] = f2bf(s[e]);
        wfrag[c] = __builtin_bit_cast(vbf16x8, t8);
    }

    for (int i = tid; i < ASTR; i += 256) { act_hp[4][i] = 0; act_in[4][i] = 0; }
    if (tid < 16) {
        bias_a[tid] = bsv[layer * NH + j0 + tid];
        bias_t[tid] = tbv[layer * NH + j0 + tid];
    }
    const float lam = softplus_f(lambda_p[0]);
    float hreg = 0.0f;                       // wave0: (j = lane&15, b = lane>>4)

    const int lm1 = (layer > 0) ? layer - 1 : 0;
    int* pf  = prod_flag + layer * NS * FSTR;   // my layer's step-done counters
    int* pfp = prod_flag + lm1  * NS * FSTR;    // prev layer's
    int* cfo = cons_flag + layer * NS * FSTR;   // my consumers' acks
    int* cfm = cons_flag + lm1  * NS * FSTR;    // my acks to prev layer

    for (int t = 0; t < NS; ++t) {
        // ---- 1. poll flags (ALL threads; relaxed sc1 loads, line-padded) ----
        {
            const bool n1 = (t > 0);
            const bool n2 = (layer > 0);
            const bool nc = (layer < 3) && (t >= RING);
            if (n1 | n2 | nc) {
                int* a1 = pf  + (t - 1) * FSTR;
                int* a2 = pfp + t * FSTR;
                int* a3 = cfo + (t - RING) * FSTR;
                for (int it = 0; it < (1 << 18); ++it) {
                    bool ok = true;
                    if (n1) ok &= (ALOAD(a1) >= 64);
                    if (n2) ok &= (ALOAD(a2) >= 64);
                    if (nc) ok &= (ALOAD(a3) >= 64);
                    if (ok) break;
                    __builtin_amdgcn_s_sleep(1);
                }
            }
        }

        // ---- 2. stage activations to LDS (lane-interleaved dwords, conflict-free) ----
        {
            const int b = wave;              // wave b stages batch row b
            u32 hv[8], iv[8];
            if (t == 0) {
#pragma unroll
                for (int i = 0; i < 8; ++i) hv[i] = 0;
            } else {
                u32* s = ring_dw + (((size_t)layer * RING + ((t - 1) & (RING - 1))) * NB + b) * 512 + lane;
#pragma unroll
                for (int i = 0; i < 8; ++i) hv[i] = ALOAD(s + 64 * i);
            }
            if (layer == 0) {
                const int v = ids[b * NS + t];
                const float* er = emb + (size_t)v * NH + lane * 2;
#pragma unroll
                for (int i = 0; i < 8; ++i) {
                    vf32x2 f = *(const vf32x2*)(er + 128 * i);
                    iv[i] = (u32)f2bf(f[0]) | ((u32)f2bf(f[1]) << 16);
                }
            } else {
                u32* s = ring_dw + (((size_t)lm1 * RING + (t & (RING - 1))) * NB + b) * 512 + lane;
#pragma unroll
                for (int i = 0; i < 8; ++i) iv[i] = ALOAD(s + 64 * i);
            }
            u32* dh = (u32*)&act_hp[b][0];
            u32* di = (u32*)&act_in[b][0];
#pragma unroll
            for (int i = 0; i < 8; ++i) { dh[lane + 64 * i] = hv[i]; di[lane + 64 * i] = iv[i]; }
        }
        __syncthreads();
        if (tid == 0 && layer > 0) AADD(cfm + t * FSTR, 1);

        // ---- 3. MFMA: out[j,b] = sum_k act[b,k] * M[j,k]; 4 accumulators ----
        {
            const u16 (*asrc)[ASTR] = ((wave & 1) == 0) ? act_hp : act_in;
            int ar = lane & 15; if (ar > 4) ar = 4;   // rows 4..15 -> zero row
            vf32x4 a0 = {0.f,0.f,0.f,0.f}, a1 = a0, a2 = a0, a3 = a0;
#pragma unroll
            for (int c = 0; c < 32; c += 4) {
                a0 = __builtin_amdgcn_mfma_f32_16x16x32_bf16(*(const vbf16x8*)&asrc[ar][(c+0)*32+kb], wfrag[c+0], a0, 0, 0, 0);
                a1 = __builtin_amdgcn_mfma_f32_16x16x32_bf16(*(const vbf16x8*)&asrc[ar][(c+1)*32+kb], wfrag[c+1], a1, 0, 0, 0);
                a2 = __builtin_amdgcn_mfma_f32_16x16x32_bf16(*(const vbf16x8*)&asrc[ar][(c+2)*32+kb], wfrag[c+2], a2, 0, 0, 0);
                a3 = __builtin_amdgcn_mfma_f32_16x16x32_bf16(*(const vbf16x8*)&asrc[ar][(c+3)*32+kb], wfrag[c+3], a3, 0, 0, 0);
            }
            vf32x4 acc = (a0 + a1) + (a2 + a3);
            if (lane < 16) {
#pragma unroll
                for (int r = 0; r < 4; ++r) cross[wave][lane][r] = acc[r];
            }
        }
        __syncthreads();

        // ---- 4. finalize + publish (wave 0); data->flag ordered by vmcnt(0) ----
        if (wave == 0) {
            const int j = lane & 15, b = lane >> 4;
            const float sa = cross[0][j][b] + cross[1][j][b] + bias_a[j];
            const float st = cross[2][j][b] + cross[3][j][b] + bias_t[j];
            const float tau = softplus_f(st) + 0.01f;
            const float a   = tanhf(sa);
            float dx = lam * (a - hreg / tau);
            dx = fminf(10.0f, fmaxf(-10.0f, dx));
            hreg = fmaf(0.1f, dx, hreg);
            const u32 hb = f2bf(hreg);
            const u32 up = (u32)__shfl_down((int)hb, 1);
            const u32 pk = hb | (up << 16);
            if ((lane & 1) == 0) {
                const size_t dwi = (((size_t)layer * RING + (t & (RING - 1))) * NB + b) * 512 + ((j0 + j) >> 1);
                ASTORE(ring_dw + dwi, pk);
                if (layer == 3) out_dw[(((size_t)b * NS + t) * NH + j0 + j) >> 1] = pk;
            }
            if (t == NS - 1) hT_out[((size_t)layer * NB + b) * NH + j0 + j] = hreg;
            asm volatile("s_waitcnt vmcnt(0)" ::: "memory");
            if (lane == 0) AADD(pf + t * FSTR, 1);
        }
    }
}

// ---------------- projection GEMM: C[2048][32000] = A[2048][1024](bf16) * W[32000][1024]^T + b ----
#define BM 128
#define BN 128
#define BK 32
#define KSTEPS (NH / BK)
#define LSTR (BK + 8)

__global__ __launch_bounds__(256, 1) void proj_gemm(
    const u16* __restrict__ A, const float* __restrict__ Bw,
    const float* __restrict__ bias, float* __restrict__ C)
{
    __shared__ __align__(16) u16 Asm[2][BM][LSTR];
    __shared__ __align__(16) u16 Bsm[2][BN][LSTR];

    const int tid  = threadIdx.x;
    const int wave = tid >> 6, lane = tid & 63;
    const int wr = wave >> 1, wc = wave & 1;

    // XCD-chunked bijective swizzle, m-fastest: each XCD works one n-panel of B
    // across all 16 m-tiles before moving on -> B panel served from L2/IF$.
    const int nwg = gridDim.x;
    const int id  = blockIdx.x;
    const int q = nwg >> 3, r = nwg & 7;
    const int x = id & 7, o = id >> 3;
    const int wg = (x < r ? x * (q + 1) : r * (q + 1) + (x - r) * q) + o;
    const int m0 = (wg & 15) * BM;
    const int n0 = (wg >> 4) * BN;

    const int srow  = tid >> 1;
    const int shalf = tid & 1;
    const u16*   agp = A  + (size_t)(m0 + srow) * NH + shalf * 16;
    const float* bgp = Bw + (size_t)(n0 + srow) * NH + shalf * 16;

    vf32x4 zed = {0.f, 0.f, 0.f, 0.f};
    vf32x4 acc[4][4];
#pragma unroll
    for (int m = 0; m < 4; ++m)
#pragma unroll
        for (int n = 0; n < 4; ++n) acc[m][n] = zed;

    vu32x4 areg0, areg1; vf32x4 breg0, breg1, breg2, breg3;
    auto load_tile = [&](int kt) {
        const u16* ap = agp + kt * BK;
        areg0 = *(const vu32x4*)ap;
        areg1 = *(const vu32x4*)(ap + 8);
        const float* bp = bgp + kt * BK;
        breg0 = *(const vf32x4*)bp;       breg1 = *(const vf32x4*)(bp + 4);
        breg2 = *(const vf32x4*)(bp + 8); breg3 = *(const vf32x4*)(bp + 12);
    };
    auto write_tile = [&](int buf) {
        u16* ad = &Asm[buf][srow][shalf * 16];
        *(vu32x4*)ad = areg0; *(vu32x4*)(ad + 8) = areg1;
        float fb[16];
        *(vf32x4*)&fb[0] = breg0; *(vf32x4*)&fb[4]  = breg1;
        *(vf32x4*)&fb[8] = breg2; *(vf32x4*)&fb[12] = breg3;
        vu16x8 v0, v1;
#pragma unroll
        for (int e = 0; e < 8; ++e) { v0[e] = f2bf(fb[e]); v1[e] = f2bf(fb[8 + e]); }
        u16* bd = &Bsm[buf][srow][shalf * 16];
        *(vu16x8*)bd = v0; *(vu16x8*)(bd + 8) = v1;
    };

    load_tile(0); write_tile(0);
    __syncthreads();

    const int fr = lane & 15;
    const int fk = (lane >> 4) * 8;
    for (int kt = 0; kt < KSTEPS; ++kt) {
        const int cur = kt & 1;
        if (kt + 1 < KSTEPS) load_tile(kt + 1);   // issue-early (T14)
        vbf16x8 afr[4], bfr[4];
#pragma unroll
        for (int m = 0; m < 4; ++m)
            afr[m] = *(const vbf16x8*)&Asm[cur][wr * 64 + m * 16 + fr][fk];
#pragma unroll
        for (int n = 0; n < 4; ++n)
            bfr[n] = *(const vbf16x8*)&Bsm[cur][wc * 64 + n * 16 + fr][fk];
#pragma unroll
        for (int m = 0; m < 4; ++m)
#pragma unroll
            for (int n = 0; n < 4; ++n)
                acc[m][n] = __builtin_amdgcn_mfma_f32_16x16x32_bf16(afr[m], bfr[n], acc[m][n], 0, 0, 0);
        if (kt + 1 < KSTEPS) write_tile(cur ^ 1); // write-late
        __syncthreads();
    }

    const int cc = lane & 15;
    const int cr = (lane >> 4) * 4;
#pragma unroll
    for (int m = 0; m < 4; ++m) {
#pragma unroll
        for (int n = 0; n < 4; ++n) {
            const int gc = n0 + wc * 64 + n * 16 + cc;
            const float bval = bias[gc];
            float* cp = C + (size_t)(m0 + wr * 64 + m * 16 + cr) * NV + gc;
#pragma unroll
            for (int r = 0; r < 4; ++r)
                cp[(size_t)r * NV] = acc[m][n][r] + bval;
        }
    }
}

extern "C" void kernel_launch(void* const* d_in, const int* in_sizes, int n_in,
                              void* d_out, int out_size, void* d_ws, size_t ws_size,
                              hipStream_t stream) {
    const int*   ids = (const int*)  d_in[0];
    const float* emb = (const float*)d_in[1];
    const float* pw  = (const float*)d_in[2];
    const float* pb  = (const float*)d_in[3];
    const float* lam = (const float*)d_in[4];
    const float* Ws  = (const float*)d_in[5];
    const float* Us  = (const float*)d_in[6];
    const float* bsv = (const float*)d_in[7];
    const float* twh = (const float*)d_in[8];
    const float* twu = (const float*)d_in[9];
    const float* tbv = (const float*)d_in[10];

    char* ws = (char*)d_ws;
    int* prod_flag = (int*)ws;                           // 4*512*16*4 = 128 KB
    int* cons_flag = (int*)(ws + 131072);                // 128 KB
    u32* ring_dw   = (u32*)(ws + 262144);                // 4*8*4*1024*2 = 256 KB
    u16* out_bf16  = (u16*)(ws + 524288);                // 2048*1024*2 = 4 MB

    float* logits = (float*)d_out;
    float* hT     = logits + (size_t)NB * NS * NV;

    hipMemsetAsync(prod_flag, 0, 262144, stream);        // both flag arrays, every call
    lnn_recur<<<dim3(256), dim3(256), 0, stream>>>(ids, emb, Ws, Us, bsv, twh, twu, tbv, lam,
                                                   prod_flag, cons_flag, ring_dw, (u32*)out_bf16, hT);
    proj_gemm<<<dim3((NV / BN) * ((NB * NS) / BM)), dim3(256), 0, stream>>>(out_bf16, pw, pb, logits);
}